// Round 22
// baseline (5932.016 us; speedup 1.0000x reference)
//
#include <hip/hip_runtime.h>
#include <math.h>

#define DD 64
#define NSWEEP 7

typedef float f32x2 __attribute__((ext_vector_type(2)));

__device__ __forceinline__ float rdlane(float v, int l) {
    return __int_as_float(__builtin_amdgcn_readlane(__float_as_int(v), l));
}
__device__ __forceinline__ float bperm(int paddr, float v) {
    return __int_as_float(__builtin_amdgcn_ds_bpermute(paddr, __float_as_int(v)));
}

// ------------- Kernel 0: symmetrize + Cholesky, L -> d_out (stash) -----------
// One wave per matrix; the proven r7/r11 codepath (VGPR ~84, no spill under
// the (64,2)=128-cap bracket). Isolating the w[64] register peak here keeps
// the sweep kernel's allocation flat (r21 lesson: a one-phase peak forces a
// whole-kernel spill).
__global__ __launch_bounds__(64, 2)
void logeig_chol_kernel(const float* __restrict__ X, float* __restrict__ Lout, int nb) {
    const int b = blockIdx.x;
    if (b >= nb) return;
    const int lane = threadIdx.x & 63;
    const float* Xb = X + (size_t)b * DD * DD;

    float w[DD];
    #pragma unroll
    for (int e = 0; e < DD; ++e)
        w[e] = 0.5f * (Xb[e * DD + lane] + Xb[lane * DD + e]);

    #pragma unroll
    for (int k = 0; k < DD; ++k) {
        const float pivot = rdlane(w[k], k);
        const float rinv  = 1.0f / sqrtf(pivot);
        const float ljk   = w[k] * rinv;
        const bool  gtk   = (lane > k);
        const bool  eqk   = (lane == k);
        #pragma unroll
        for (int e = k; e < DD; ++e) {
            const float lek = rdlane(w[e], k) * rinv;
            const float upd = fmaf(-lek, ljk, w[e]);
            w[e] = eqk ? lek : (gtk ? upd : w[e]);
        }
    }
    #pragma unroll
    for (int e = 0; e < DD - 1; ++e)
        if (e < lane) w[e] = 0.0f;

    float* Lb = Lout + (size_t)b * DD * DD;
    #pragma unroll
    for (int e = 0; e < DD; ++e)
        Lb[e * DD + lane] = w[e];    // coalesced
}

// ------------- Kernel 1: split-column one-sided Jacobi sweeps ----------------
// 2 waves per matrix; wave h holds elements [32h,32h+32) of column `lane`
// (w2[16] packed). w2+oth2 = 64 regs BOTH live -> no bpermute remat:
// ~70 DS-ops/matrix/stage vs 129 (the validated 5.5ms wall). Cross-wave dot
// via parity-double-buffered LDS + 1 barrier/stage (WAR-safe: slot rewritten
// only 2 barriers later). (c,s) bitwise-identical in both waves and both
// lanes of a pair (same summation order everywhere).
__global__ __launch_bounds__(128, 1)
void logeig_sweeps_kernel(float* __restrict__ Wbuf, int nb) {
    __shared__ float hd[2][2][DD];   // [parity][wave][lane]
    __shared__ float hn[2][DD];

    const int b = blockIdx.x;
    if (b >= nb) return;
    const int tid  = threadIdx.x;
    const int lane = tid & 63;
    const int h    = tid >> 6;
    float* Wb = Wbuf + (size_t)b * DD * DD;

    // Load this wave's half of column `lane` (coalesced).
    f32x2 w2[16];
    #pragma unroll
    for (int i = 0; i < 16; ++i) {
        w2[i].x = Wb[(h * 32 + 2 * i) * DD + lane];
        w2[i].y = Wb[(h * 32 + 2 * i + 1) * DD + lane];
    }

    // Initial norm via half-norm exchange (same add order in both waves).
    {
        f32x2 a0 = {0.f, 0.f}, a1 = {0.f, 0.f};
        #pragma unroll
        for (int i = 0; i < 16; i += 2) {
            a0 = w2[i] * w2[i] + a0;
            a1 = w2[i + 1] * w2[i + 1] + a1;
        }
        hn[h][lane] = (a0.x + a0.y) + (a1.x + a1.y);
    }
    __syncthreads();
    float nown = hn[0][lane] + hn[1][lane];

    const int lane4 = lane << 2;
    int g = 0;

    for (int sw = 0; sw < NSWEEP; ++sw) {
        bool sweep_rotated = false;
        for (int m = 1; m < DD; ++m, ++g) {
            const int paddr = lane4 ^ (m << 2);
            const int par   = g & 1;

            f32x2 oth2[16];
            #pragma unroll
            for (int i = 0; i < 16; ++i) {
                oth2[i].x = bperm(paddr, w2[i].x);
                oth2[i].y = bperm(paddr, w2[i].y);
            }

            f32x2 dv0 = {0.f, 0.f}, dv1 = {0.f, 0.f};
            #pragma unroll
            for (int i = 0; i < 16; i += 2) {
                dv0 = w2[i] * oth2[i] + dv0;
                dv1 = w2[i + 1] * oth2[i + 1] + dv1;
            }
            hd[par][h][lane] = (dv0.x + dv0.y) + (dv1.x + dv1.y);
            const float noth = bperm(paddr, nown);
            __syncthreads();
            const float d = hd[par][0][lane] + hd[par][1][lane];

            // Relative tol 1e-4 (absmax-neutral, rounds 9-21).
            const bool dorot = (d * d > 1e-8f * nown * noth);
            if (__any(dorot)) {   // uniform across both waves (d,nown,noth identical)
                sweep_rotated = true;
                const bool  islo = (paddr > lane4);
                const float app  = islo ? nown : noth;
                const float aqq  = islo ? noth : nown;
                float tau = (aqq - app) * 0.5f / d;
                float t   = 1.0f / (fabsf(tau) + sqrtf(fmaf(tau, tau, 1.0f)));
                t = copysignf(t, tau);
                float c = 1.0f / sqrtf(fmaf(t, t, 1.0f));
                float s = t * c;
                float tsgn = islo ? -t : t;
                if (!islo) s = -s;
                if (!dorot) { c = 1.0f; s = 0.0f; tsgn = 0.0f; }
                nown = fmaf(tsgn, d, nown);

                const f32x2 c2 = {c, c};
                const f32x2 s2 = {s, s};
                #pragma unroll
                for (int i = 0; i < 16; ++i)
                    w2[i] = c2 * w2[i] - s2 * oth2[i];
            }
        }
        if (!sweep_rotated) break;
    }

    // Write W back in place (block-local region only).
    #pragma unroll
    for (int i = 0; i < 16; ++i) {
        Wb[(h * 32 + 2 * i) * DD + lane]     = w2[i].x;
        Wb[(h * 32 + 2 * i + 1) * DD + lane] = w2[i].y;
    }
}

// ------------- Kernel 2: epilogue out = W diag(scl) W^T (in place) -----------
__global__ __launch_bounds__(256, 2)
void logeig_epilogue_kernel(float* __restrict__ out, int nb) {
    __shared__ float M[DD][DD + 1];
    __shared__ float sc[DD];

    const int b = blockIdx.x;
    if (b >= nb) return;
    const int tid  = threadIdx.x;
    const int lane = tid & 63;
    const int w4   = tid >> 6;
    float* Ob = out + (size_t)b * DD * DD;

    #pragma unroll
    for (int ii = 0; ii < 16; ++ii) {
        int r = w4 * 16 + ii;
        M[r][lane] = Ob[r * DD + lane];
    }
    __syncthreads();

    if (tid < DD) {
        float n0 = 0.f, n1 = 0.f;
        #pragma unroll
        for (int e = 0; e < DD; e += 2) {
            n0 = fmaf(M[e][tid],     M[e][tid],     n0);
            n1 = fmaf(M[e + 1][tid], M[e + 1][tid], n1);
        }
        const float nn = n0 + n1;                    // lambda_j
        sc[tid] = logf(fmaxf(nn, 1e-7f)) / nn;       // log(clip(lam))/lam
    }
    __syncthreads();

    float vrow[DD];
    #pragma unroll
    for (int j = 0; j < DD; ++j) vrow[j] = M[lane][j] * sc[j];

    float acc[16];
    #pragma unroll
    for (int ii = 0; ii < 16; ++ii) acc[ii] = 0.0f;

    for (int k = 0; k < DD; ++k) {
        const float vl = vrow[k];
        #pragma unroll
        for (int ii = 0; ii < 16; ++ii)
            acc[ii] = fmaf(M[w4 * 16 + ii][k], vl, acc[ii]);
    }

    __syncthreads();
    #pragma unroll
    for (int ii = 0; ii < 16; ++ii)
        Ob[(size_t)(w4 * 16 + ii) * DD + lane] = acc[ii];
}

extern "C" void kernel_launch(void* const* d_in, const int* in_sizes, int n_in,
                              void* d_out, int out_size, void* d_ws, size_t ws_size,
                              hipStream_t stream) {
    (void)n_in; (void)d_ws; (void)ws_size; (void)out_size;
    const float* X = (const float*)d_in[0];
    float* out = (float*)d_out;
    int nb = in_sizes[0] / (DD * DD);
    hipLaunchKernelGGL(logeig_chol_kernel,     dim3(nb), dim3(64),  0, stream, X, out, nb);
    hipLaunchKernelGGL(logeig_sweeps_kernel,   dim3(nb), dim3(128), 0, stream, out, nb);
    hipLaunchKernelGGL(logeig_epilogue_kernel, dim3(nb), dim3(256), 0, stream, out, nb);
}

// Round 23
// 5769.825 us; speedup vs baseline: 1.0281x; 1.0281x over previous
//
#include <hip/hip_runtime.h>
#include <math.h>

#define DD 64
#define NSWEEP 7

typedef float f32x2 __attribute__((ext_vector_type(2)));

__device__ __forceinline__ float rdlane(float v, int l) {
    return __int_as_float(__builtin_amdgcn_readlane(__float_as_int(v), l));
}
__device__ __forceinline__ float bperm(int paddr, float v) {
    return __int_as_float(__builtin_amdgcn_ds_bpermute(paddr, __float_as_int(v)));
}

// ------------- Kernel 0: symmetrize + Cholesky, L -> d_out (stash) -----------
// Proven r7/r22 codepath: one wave/matrix, VGPR ~84, no spill at (64,2).
__global__ __launch_bounds__(64, 2)
void logeig_chol_kernel(const float* __restrict__ X, float* __restrict__ Lout, int nb) {
    const int b = blockIdx.x;
    if (b >= nb) return;
    const int lane = threadIdx.x & 63;
    const float* Xb = X + (size_t)b * DD * DD;

    float w[DD];
    #pragma unroll
    for (int e = 0; e < DD; ++e)
        w[e] = 0.5f * (Xb[e * DD + lane] + Xb[lane * DD + e]);

    #pragma unroll
    for (int k = 0; k < DD; ++k) {
        const float pivot = rdlane(w[k], k);
        const float rinv  = 1.0f / sqrtf(pivot);
        const float ljk   = w[k] * rinv;
        const bool  gtk   = (lane > k);
        const bool  eqk   = (lane == k);
        #pragma unroll
        for (int e = k; e < DD; ++e) {
            const float lek = rdlane(w[e], k) * rinv;
            const float upd = fmaf(-lek, ljk, w[e]);
            w[e] = eqk ? lek : (gtk ? upd : w[e]);
        }
    }
    #pragma unroll
    for (int e = 0; e < DD - 1; ++e)
        if (e < lane) w[e] = 0.0f;

    float* Lb = Lout + (size_t)b * DD * DD;
    #pragma unroll
    for (int e = 0; e < DD; ++e)
        Lb[e * DD + lane] = w[e];    // coalesced
}

// ------------- Kernel 1: split-column caterpillar Jacobi sweeps --------------
// Lane (j,h): j=lane&31 slot, h=lane>>5 half. Holds elements [32h,32h+32) of
// T_j = moving col (init col j) and B_j = moving col (init col 63-j).
// Dot T.B is half-local + ONE bperm(lane^32) combine (fixed-order sum ->
// bitwise-identical d in both halves). Rotation is lane-local. March
// (r17-proven tournament): T_j<-T_{j+1}, B_j<-B_{j-1}, T_31<-B_31, B_0<-T_1,
// T_0 fixed; period 63 -> layout returns to initial at each sweep boundary.
// NO value is fetched-then-reused -> bpermute remat impossible (the r8-r22
// wall). 67 DS-ops/matrix/stage vs 129. Zero barriers, zero LDS.
__global__ __launch_bounds__(64, 2)
void logeig_sweeps_kernel(float* __restrict__ Wbuf, int nb) {
    const int b = blockIdx.x;
    if (b >= nb) return;
    const int lane = threadIdx.x & 63;
    const int j    = lane & 31;
    const int h    = lane >> 5;
    float* Wb = Wbuf + (size_t)b * DD * DD;

    // Load this lane's halves of T (col j) and B (col 63-j), packed.
    f32x2 T2[16], B2[16];
    #pragma unroll
    for (int i = 0; i < 16; ++i) {
        const int e0 = 32 * h + 2 * i, e1 = e0 + 1;
        T2[i].x = Wb[e0 * DD + j];        T2[i].y = Wb[e1 * DD + j];
        B2[i].x = Wb[e0 * DD + (63 - j)]; B2[i].y = Wb[e1 * DD + (63 - j)];
    }

    const int xaddr = (lane ^ 32) << 2;   // half-partner (other h, same j)

    // Initial full-column norms via one cross-half exchange (fixed add order).
    float nT, nB;
    {
        f32x2 a = {0.f, 0.f}, c_ = {0.f, 0.f};
        #pragma unroll
        for (int i = 0; i < 16; ++i) {
            a  = T2[i] * T2[i] + a;
            c_ = B2[i] * B2[i] + c_;
        }
        const float hT = a.x + a.y, hB = c_.x + c_.y;
        const float oT = bperm(xaddr, hT), oB = bperm(xaddr, hB);
        nT = (h == 0) ? (hT + oT) : (oT + hT);   // = hn(h=0)+hn(h=1) both ways
        nB = (h == 0) ? (hB + oB) : (oB + hB);
    }

    // March addressing (hoisted, within the same h group).
    const int addrA = ((h << 5) | ((j + 1) & 31)) << 2;    // lane (j+1,h)
    const int addrB = ((h << 5) | ((j + 31) & 31)) << 2;   // lane (j-1,h)
    const bool isJ0 = (j == 0), isJ31 = (j == 31);

    for (int sw = 0; sw < NSWEEP; ++sw) {
        bool rotated = false;
        for (int t = 0; t < 63; ++t) {
            // Half-dot + one-bperm combine (identical d in both halves).
            f32x2 dv0 = {0.f, 0.f}, dv1 = {0.f, 0.f};
            #pragma unroll
            for (int i = 0; i < 16; i += 2) {
                dv0 = T2[i] * B2[i] + dv0;
                dv1 = T2[i + 1] * B2[i + 1] + dv1;
            }
            const float hd = (dv0.x + dv0.y) + (dv1.x + dv1.y);
            const float ho = bperm(xaddr, hd);
            const float d  = (h == 0) ? (hd + ho) : (ho + hd);

            const bool dorot = (d * d > 1e-8f * nT * nB);
            rotated = rotated || __any(dorot);

            // Coefficients, lane-local (p = T, q = B; r17-proven convention).
            float tau = (nB - nT) * 0.5f / d;
            float tt  = 1.0f / (fabsf(tau) + sqrtf(fmaf(tau, tau, 1.0f)));
            tt = copysignf(tt, tau);
            float c = 1.0f / sqrtf(fmaf(tt, tt, 1.0f));
            float s = tt * c;
            if (!dorot) { c = 1.0f; s = 0.0f; tt = 0.0f; }
            nT = fmaf(-tt, d, nT);
            nB = fmaf( tt, d, nB);

            // Rotate + march, fused per packed element (bperm results are
            // consumed immediately into mutated state -> no remat possible).
            const f32x2 c2 = {c, c};
            const f32x2 s2 = {s, s};
            #pragma unroll
            for (int i = 0; i < 16; ++i) {
                const f32x2 x = T2[i], y = B2[i];
                const f32x2 rx = c2 * x - s2 * y;    // new T (pre-march)
                const f32x2 ry = s2 * x + c2 * y;    // new B (pre-march)
                const float tAx = bperm(addrA, rx.x);
                const float tAy = bperm(addrA, rx.y);
                const float tBx = bperm(addrB, ry.x);
                const float tBy = bperm(addrB, ry.y);
                T2[i].x = isJ0 ? rx.x : (isJ31 ? ry.x : tAx);
                T2[i].y = isJ0 ? rx.y : (isJ31 ? ry.y : tAy);
                B2[i].x = isJ0 ? tAx : tBx;          // lane0: tA == T_1
                B2[i].y = isJ0 ? tAy : tBy;
            }
            // March the norms identically.
            {
                const float mA = bperm(addrA, nT);
                const float mB = bperm(addrB, nB);
                const float newT = isJ0 ? nT : (isJ31 ? nB : mA);
                const float newB = isJ0 ? mA : mB;
                nT = newT; nB = newB;
            }
        }
        if (!rotated) break;   // layout is at initial at sweep boundaries
    }

    // Stash W back in place (layout == initial).
    #pragma unroll
    for (int i = 0; i < 16; ++i) {
        const int e0 = 32 * h + 2 * i, e1 = e0 + 1;
        Wb[e0 * DD + j]        = T2[i].x;
        Wb[e1 * DD + j]        = T2[i].y;
        Wb[e0 * DD + (63 - j)] = B2[i].x;
        Wb[e1 * DD + (63 - j)] = B2[i].y;
    }
}

// ------------- Kernel 2: epilogue out = W diag(scl) W^T (in place) -----------
__global__ __launch_bounds__(256, 2)
void logeig_epilogue_kernel(float* __restrict__ out, int nb) {
    __shared__ float M[DD][DD + 1];
    __shared__ float sc[DD];

    const int b = blockIdx.x;
    if (b >= nb) return;
    const int tid  = threadIdx.x;
    const int lane = tid & 63;
    const int w4   = tid >> 6;
    float* Ob = out + (size_t)b * DD * DD;

    #pragma unroll
    for (int ii = 0; ii < 16; ++ii) {
        int r = w4 * 16 + ii;
        M[r][lane] = Ob[r * DD + lane];
    }
    __syncthreads();

    if (tid < DD) {
        float n0 = 0.f, n1 = 0.f;
        #pragma unroll
        for (int e = 0; e < DD; e += 2) {
            n0 = fmaf(M[e][tid],     M[e][tid],     n0);
            n1 = fmaf(M[e + 1][tid], M[e + 1][tid], n1);
        }
        const float nn = n0 + n1;                    // lambda_j
        sc[tid] = logf(fmaxf(nn, 1e-7f)) / nn;       // log(clip(lam))/lam
    }
    __syncthreads();

    float vrow[DD];
    #pragma unroll
    for (int jj = 0; jj < DD; ++jj) vrow[jj] = M[lane][jj] * sc[jj];

    float acc[16];
    #pragma unroll
    for (int ii = 0; ii < 16; ++ii) acc[ii] = 0.0f;

    for (int k = 0; k < DD; ++k) {
        const float vl = vrow[k];
        #pragma unroll
        for (int ii = 0; ii < 16; ++ii)
            acc[ii] = fmaf(M[w4 * 16 + ii][k], vl, acc[ii]);
    }

    __syncthreads();
    #pragma unroll
    for (int ii = 0; ii < 16; ++ii)
        Ob[(size_t)(w4 * 16 + ii) * DD + lane] = acc[ii];
}

extern "C" void kernel_launch(void* const* d_in, const int* in_sizes, int n_in,
                              void* d_out, int out_size, void* d_ws, size_t ws_size,
                              hipStream_t stream) {
    (void)n_in; (void)d_ws; (void)ws_size; (void)out_size;
    const float* X = (const float*)d_in[0];
    float* out = (float*)d_out;
    int nb = in_sizes[0] / (DD * DD);
    hipLaunchKernelGGL(logeig_chol_kernel,     dim3(nb), dim3(64),  0, stream, X, out, nb);
    hipLaunchKernelGGL(logeig_sweeps_kernel,   dim3(nb), dim3(64),  0, stream, out, nb);
    hipLaunchKernelGGL(logeig_epilogue_kernel, dim3(nb), dim3(256), 0, stream, out, nb);
}

// Round 24
// 4506.167 us; speedup vs baseline: 1.3164x; 1.2804x over previous
//
#include <hip/hip_runtime.h>
#include <math.h>

#define DD 64
#define NSWEEP 6

typedef float f32x2 __attribute__((ext_vector_type(2)));

__device__ __forceinline__ float rdlane(float v, int l) {
    return __int_as_float(__builtin_amdgcn_readlane(__float_as_int(v), l));
}
__device__ __forceinline__ float bperm(int paddr, float v) {
    return __int_as_float(__builtin_amdgcn_ds_bpermute(paddr, __float_as_int(v)));
}

// ---------------- Kernel 1: Cholesky + one-sided Jacobi sweeps ----------------
// Plateau established (r7-r23): 17 variants spanning DS 67-134 ops/stage,
// VALU +-2x, occupancy 22-45%, 0-1 barriers ALL land at 5.5-6ms sweeps ->
// bound by the per-stage serial chain (bperm -> dot chain -> coeff chain ->
// rotate), not any pipe. Only lever left: fewer stages. This round: NSWEEP
// 7->6. Evidence: this method is at the 0.0156 fp32 floor already at 7
// sweeps (the r3 two-sided family needed 8: 6/7/8 = 0.125/0.039/0.0156),
// i.e. converges >=1 sweep faster (kappa(L) = sqrt(kappa(Xs))).
__global__ __launch_bounds__(64, 2)
void logeig_sweeps_kernel(const float* __restrict__ X, float* __restrict__ Wout, int nb) {
    const int b = blockIdx.x;
    if (b >= nb) return;
    const int lane = threadIdx.x & 63;
    const float* Xb = X + (size_t)b * DD * DD;

    // Symmetrize directly from global, packed 2 elems/reg-pair.
    f32x2 w2[DD / 2];
    #pragma unroll
    for (int i = 0; i < DD / 2; ++i) {
        const int e0 = 2 * i, e1 = 2 * i + 1;
        w2[i].x = 0.5f * (Xb[e0 * DD + lane] + Xb[lane * DD + e0]);
        w2[i].y = 0.5f * (Xb[e1 * DD + lane] + Xb[lane * DD + e1]);
    }

    // ---- In-wave right-looking Cholesky: lane j ends owning column j of L ----
    #pragma unroll
    for (int k = 0; k < DD; ++k) {
        const float pivot = rdlane(w2[k >> 1][k & 1], k);
        const float rinv  = 1.0f / sqrtf(pivot);
        const float ljk   = w2[k >> 1][k & 1] * rinv;
        const bool  gtk   = (lane > k);
        const bool  eqk   = (lane == k);
        #pragma unroll
        for (int e = k; e < DD; ++e) {
            const float we  = w2[e >> 1][e & 1];
            const float lek = rdlane(we, k) * rinv;
            const float upd = fmaf(-lek, ljk, we);
            w2[e >> 1][e & 1] = eqk ? lek : (gtk ? upd : we);
        }
    }
    #pragma unroll
    for (int e = 0; e < DD - 1; ++e)
        if (e < lane) w2[e >> 1][e & 1] = 0.0f;

    // Initial column norm^2 (maintained incrementally); packed accumulate.
    float nown;
    {
        f32x2 nv0 = {0.f, 0.f}, nv1 = {0.f, 0.f};
        #pragma unroll
        for (int i = 0; i < DD / 2; i += 2) {
            nv0 = w2[i] * w2[i] + nv0;
            nv1 = w2[i + 1] * w2[i + 1] + nv1;
        }
        nown = (nv0.x + nv0.y) + (nv1.x + nv1.y);
    }

    const int lane4 = lane << 2;

    for (int sw = 0; sw < NSWEEP; ++sw) {
        bool sweep_rotated = false;
        for (int m = 1; m < DD; ++m) {
            const int paddr = lane4 ^ (m << 2);   // partner*4 (XOR pairing)

            f32x2 oth2[DD / 2];
            #pragma unroll
            for (int i = 0; i < DD / 2; ++i) {
                oth2[i].x = bperm(paddr, w2[i].x);
                oth2[i].y = bperm(paddr, w2[i].y);
            }

            // d = w . oth, packed (identical expression both lanes of a pair;
            // elementwise products commute bitwise -> d bitwise-equal).
            f32x2 dv0 = {0.f, 0.f}, dv1 = {0.f, 0.f};
            #pragma unroll
            for (int i = 0; i < DD / 2; i += 2) {
                dv0 = w2[i] * oth2[i] + dv0;
                dv1 = w2[i + 1] * oth2[i + 1] + dv1;
            }
            const float d    = (dv0.x + dv0.y) + (dv1.x + dv1.y);
            const float noth = bperm(paddr, nown);

            // Relative threshold 1e-4 (absmax-neutral, rounds 9-23).
            const bool dorot = (d * d > 1e-8f * nown * noth);
            if (__any(dorot)) {
                sweep_rotated = true;
                const bool  islo = (paddr > lane4);   // low lane plays p
                const float app  = islo ? nown : noth;
                const float aqq  = islo ? noth : nown;
                float tau = (aqq - app) * 0.5f / d;
                float t   = 1.0f / (fabsf(tau) + sqrtf(fmaf(tau, tau, 1.0f)));
                t = copysignf(t, tau);
                float c = 1.0f / sqrtf(fmaf(t, t, 1.0f));
                float s = t * c;
                float tsgn = islo ? -t : t;           // nown' = nown -+ t*d
                if (!islo) s = -s;
                if (!dorot) { c = 1.0f; s = 0.0f; tsgn = 0.0f; }
                nown = fmaf(tsgn, d, nown);

                const f32x2 c2 = {c, c};
                const f32x2 s2 = {s, s};
                #pragma unroll
                for (int i = 0; i < DD / 2; ++i)
                    w2[i] = c2 * w2[i] - s2 * oth2[i];
            }
        }
        if (!sweep_rotated) break;   // identity sweep -> all later identity
    }

    // Stash W (column per lane) into d_out; epilogue kernel transforms in place.
    float* Wb = Wout + (size_t)b * DD * DD;
    #pragma unroll
    for (int e = 0; e < DD; ++e)
        Wb[e * DD + lane] = w2[e >> 1][e & 1];   // coalesced
}

// ---------------- Kernel 2: epilogue out = W diag(scl) W^T (in place) --------
__global__ __launch_bounds__(256, 2)
void logeig_epilogue_kernel(float* __restrict__ out, int nb) {
    __shared__ float M[DD][DD + 1];
    __shared__ float sc[DD];

    const int b = blockIdx.x;
    if (b >= nb) return;
    const int tid  = threadIdx.x;
    const int lane = tid & 63;
    const int w4   = tid >> 6;
    float* Ob = out + (size_t)b * DD * DD;

    #pragma unroll
    for (int ii = 0; ii < 16; ++ii) {
        int r = w4 * 16 + ii;
        M[r][lane] = Ob[r * DD + lane];
    }
    __syncthreads();

    if (tid < DD) {
        float n0 = 0.f, n1 = 0.f;
        #pragma unroll
        for (int e = 0; e < DD; e += 2) {
            n0 = fmaf(M[e][tid],     M[e][tid],     n0);
            n1 = fmaf(M[e + 1][tid], M[e + 1][tid], n1);
        }
        const float nn = n0 + n1;                    // lambda_j
        sc[tid] = logf(fmaxf(nn, 1e-7f)) / nn;       // log(clip(lam))/lam
    }
    __syncthreads();

    float vrow[DD];
    #pragma unroll
    for (int j = 0; j < DD; ++j) vrow[j] = M[lane][j] * sc[j];

    float acc[16];
    #pragma unroll
    for (int ii = 0; ii < 16; ++ii) acc[ii] = 0.0f;

    for (int k = 0; k < DD; ++k) {
        const float vl = vrow[k];
        #pragma unroll
        for (int ii = 0; ii < 16; ++ii)
            acc[ii] = fmaf(M[w4 * 16 + ii][k], vl, acc[ii]);   // broadcast reads
    }

    __syncthreads();   // all reads of W done before overwriting
    #pragma unroll
    for (int ii = 0; ii < 16; ++ii)
        Ob[(size_t)(w4 * 16 + ii) * DD + lane] = acc[ii];
}

extern "C" void kernel_launch(void* const* d_in, const int* in_sizes, int n_in,
                              void* d_out, int out_size, void* d_ws, size_t ws_size,
                              hipStream_t stream) {
    (void)n_in; (void)d_ws; (void)ws_size; (void)out_size;
    const float* X = (const float*)d_in[0];
    float* out = (float*)d_out;
    int nb = in_sizes[0] / (DD * DD);
    hipLaunchKernelGGL(logeig_sweeps_kernel, dim3(nb), dim3(DD), 0, stream, X, out, nb);
    hipLaunchKernelGGL(logeig_epilogue_kernel, dim3(nb), dim3(256), 0, stream, out, nb);
}

// Round 26
// 4505.416 us; speedup vs baseline: 1.3166x; 1.0002x over previous
//
#include <hip/hip_runtime.h>
#include <math.h>

#define DD 64
#define NSWEEP 6

typedef float f32x2 __attribute__((ext_vector_type(2)));

__device__ __forceinline__ float rdlane(float v, int l) {
    return __int_as_float(__builtin_amdgcn_readlane(__float_as_int(v), l));
}
__device__ __forceinline__ float bperm(int paddr, float v) {
    return __int_as_float(__builtin_amdgcn_ds_bpermute(paddr, __float_as_int(v)));
}

// ---------------- Kernel 1: Cholesky + one-sided Jacobi sweeps ----------------
// FINAL (r24 champion, reverted from the failed r25 NSWEEP=5 probe:
// 5 sweeps -> absmax 0.086 > 0.066; 6 sweeps -> 0.0156 = fp32 floor).
// Bound: per-stage serial chain (bperm -> dot chain -> coeff chain w/ 3
// transcendentals -> rotate) at ~0.8ms/sweep, invariant across 17 structural
// variants (DS 67-134 ops/stage, VALU +-2x, occupancy 22-45%, 0-1 barriers).
// Sweep count at its numerical minimum. 40.2ms (r1) -> 4.51ms = 8.9x.
__global__ __launch_bounds__(64, 2)
void logeig_sweeps_kernel(const float* __restrict__ X, float* __restrict__ Wout, int nb) {
    const int b = blockIdx.x;
    if (b >= nb) return;
    const int lane = threadIdx.x & 63;
    const float* Xb = X + (size_t)b * DD * DD;

    // Symmetrize directly from global, packed 2 elems/reg-pair.
    f32x2 w2[DD / 2];
    #pragma unroll
    for (int i = 0; i < DD / 2; ++i) {
        const int e0 = 2 * i, e1 = 2 * i + 1;
        w2[i].x = 0.5f * (Xb[e0 * DD + lane] + Xb[lane * DD + e0]);
        w2[i].y = 0.5f * (Xb[e1 * DD + lane] + Xb[lane * DD + e1]);
    }

    // ---- In-wave right-looking Cholesky: lane j ends owning column j of L ----
    #pragma unroll
    for (int k = 0; k < DD; ++k) {
        const float pivot = rdlane(w2[k >> 1][k & 1], k);
        const float rinv  = 1.0f / sqrtf(pivot);
        const float ljk   = w2[k >> 1][k & 1] * rinv;
        const bool  gtk   = (lane > k);
        const bool  eqk   = (lane == k);
        #pragma unroll
        for (int e = k; e < DD; ++e) {
            const float we  = w2[e >> 1][e & 1];
            const float lek = rdlane(we, k) * rinv;
            const float upd = fmaf(-lek, ljk, we);
            w2[e >> 1][e & 1] = eqk ? lek : (gtk ? upd : we);
        }
    }
    #pragma unroll
    for (int e = 0; e < DD - 1; ++e)
        if (e < lane) w2[e >> 1][e & 1] = 0.0f;

    // Initial column norm^2 (maintained incrementally); packed accumulate.
    float nown;
    {
        f32x2 nv0 = {0.f, 0.f}, nv1 = {0.f, 0.f};
        #pragma unroll
        for (int i = 0; i < DD / 2; i += 2) {
            nv0 = w2[i] * w2[i] + nv0;
            nv1 = w2[i + 1] * w2[i + 1] + nv1;
        }
        nown = (nv0.x + nv0.y) + (nv1.x + nv1.y);
    }

    const int lane4 = lane << 2;

    for (int sw = 0; sw < NSWEEP; ++sw) {
        bool sweep_rotated = false;
        for (int m = 1; m < DD; ++m) {
            const int paddr = lane4 ^ (m << 2);   // partner*4 (XOR pairing)

            f32x2 oth2[DD / 2];
            #pragma unroll
            for (int i = 0; i < DD / 2; ++i) {
                oth2[i].x = bperm(paddr, w2[i].x);
                oth2[i].y = bperm(paddr, w2[i].y);
            }

            // d = w . oth, packed (identical expression both lanes of a pair;
            // elementwise products commute bitwise -> d bitwise-equal).
            f32x2 dv0 = {0.f, 0.f}, dv1 = {0.f, 0.f};
            #pragma unroll
            for (int i = 0; i < DD / 2; i += 2) {
                dv0 = w2[i] * oth2[i] + dv0;
                dv1 = w2[i + 1] * oth2[i + 1] + dv1;
            }
            const float d    = (dv0.x + dv0.y) + (dv1.x + dv1.y);
            const float noth = bperm(paddr, nown);

            // Relative threshold 1e-4 (absmax-neutral, rounds 9-24).
            const bool dorot = (d * d > 1e-8f * nown * noth);
            if (__any(dorot)) {
                sweep_rotated = true;
                const bool  islo = (paddr > lane4);   // low lane plays p
                const float app  = islo ? nown : noth;
                const float aqq  = islo ? noth : nown;
                float tau = (aqq - app) * 0.5f / d;
                float t   = 1.0f / (fabsf(tau) + sqrtf(fmaf(tau, tau, 1.0f)));
                t = copysignf(t, tau);
                float c = 1.0f / sqrtf(fmaf(t, t, 1.0f));
                float s = t * c;
                float tsgn = islo ? -t : t;           // nown' = nown -+ t*d
                if (!islo) s = -s;
                if (!dorot) { c = 1.0f; s = 0.0f; tsgn = 0.0f; }
                nown = fmaf(tsgn, d, nown);

                const f32x2 c2 = {c, c};
                const f32x2 s2 = {s, s};
                #pragma unroll
                for (int i = 0; i < DD / 2; ++i)
                    w2[i] = c2 * w2[i] - s2 * oth2[i];
            }
        }
        if (!sweep_rotated) break;   // identity sweep -> all later identity
    }

    // Stash W (column per lane) into d_out; epilogue kernel transforms in place.
    float* Wb = Wout + (size_t)b * DD * DD;
    #pragma unroll
    for (int e = 0; e < DD; ++e)
        Wb[e * DD + lane] = w2[e >> 1][e & 1];   // coalesced
}

// ---------------- Kernel 2: epilogue out = W diag(scl) W^T (in place) --------
__global__ __launch_bounds__(256, 2)
void logeig_epilogue_kernel(float* __restrict__ out, int nb) {
    __shared__ float M[DD][DD + 1];
    __shared__ float sc[DD];

    const int b = blockIdx.x;
    if (b >= nb) return;
    const int tid  = threadIdx.x;
    const int lane = tid & 63;
    const int w4   = tid >> 6;
    float* Ob = out + (size_t)b * DD * DD;

    #pragma unroll
    for (int ii = 0; ii < 16; ++ii) {
        int r = w4 * 16 + ii;
        M[r][lane] = Ob[r * DD + lane];
    }
    __syncthreads();

    if (tid < DD) {
        float n0 = 0.f, n1 = 0.f;
        #pragma unroll
        for (int e = 0; e < DD; e += 2) {
            n0 = fmaf(M[e][tid],     M[e][tid],     n0);
            n1 = fmaf(M[e + 1][tid], M[e + 1][tid], n1);
        }
        const float nn = n0 + n1;                    // lambda_j
        sc[tid] = logf(fmaxf(nn, 1e-7f)) / nn;       // log(clip(lam))/lam
    }
    __syncthreads();

    float vrow[DD];
    #pragma unroll
    for (int j = 0; j < DD; ++j) vrow[j] = M[lane][j] * sc[j];

    float acc[16];
    #pragma unroll
    for (int ii = 0; ii < 16; ++ii) acc[ii] = 0.0f;

    for (int k = 0; k < DD; ++k) {
        const float vl = vrow[k];
        #pragma unroll
        for (int ii = 0; ii < 16; ++ii)
            acc[ii] = fmaf(M[w4 * 16 + ii][k], vl, acc[ii]);   // broadcast reads
    }

    __syncthreads();   // all reads of W done before overwriting
    #pragma unroll
    for (int ii = 0; ii < 16; ++ii)
        Ob[(size_t)(w4 * 16 + ii) * DD + lane] = acc[ii];
}

extern "C" void kernel_launch(void* const* d_in, const int* in_sizes, int n_in,
                              void* d_out, int out_size, void* d_ws, size_t ws_size,
                              hipStream_t stream) {
    (void)n_in; (void)d_ws; (void)ws_size; (void)out_size;
    const float* X = (const float*)d_in[0];
    float* out = (float*)d_out;
    int nb = in_sizes[0] / (DD * DD);
    hipLaunchKernelGGL(logeig_sweeps_kernel, dim3(nb), dim3(DD), 0, stream, X, out, nb);
    hipLaunchKernelGGL(logeig_epilogue_kernel, dim3(nb), dim3(256), 0, stream, out, nb);
}